// Round 1
// baseline (599.842 us; speedup 1.0000x reference)
//
#include <hip/hip_runtime.h>
#include <cstdint>
#include <cstddef>

// GraphSAGE 3-layer, N=100000 nodes, E=1600000 edges, dims 64->64->64->32.
// Strategy: transform-then-aggregate (linearity of segment_sum), CSR built once
// per launch and reused for all 3 layers, atomic-free gather.

// ---------------- CSR build ----------------

__global__ __launch_bounds__(256) void count_deg(const int* __restrict__ dst,
                                                 int* __restrict__ deg, int E) {
  int e = blockIdx.x * 256 + threadIdx.x;
  if (e < E) atomicAdd(&deg[dst[e]], 1);
}

__global__ __launch_bounds__(256) void scan_blocks(const int* __restrict__ deg,
                                                   int* __restrict__ rowptr,
                                                   int* __restrict__ bsum, int N) {
  __shared__ int sh[256];
  int tid = threadIdx.x;
  int i = blockIdx.x * 256 + tid;
  int v = (i < N) ? deg[i] : 0;
  sh[tid] = v;
  __syncthreads();
  for (int off = 1; off < 256; off <<= 1) {
    int x = sh[tid];
    if (tid >= off) x += sh[tid - off];
    __syncthreads();
    sh[tid] = x;
    __syncthreads();
  }
  if (i < N) rowptr[i] = sh[tid] - v;       // block-local exclusive
  if (tid == 255) bsum[blockIdx.x] = sh[tid];
}

// nb <= 512 required (N <= 131072; here nb = 391)
__global__ __launch_bounds__(512) void scan_tops(int* bsum, int nb) {
  __shared__ int sh[512];
  int tid = threadIdx.x;
  int v = (tid < nb) ? bsum[tid] : 0;
  sh[tid] = v;
  __syncthreads();
  for (int off = 1; off < 512; off <<= 1) {
    int x = sh[tid];
    if (tid >= off) x += sh[tid - off];
    __syncthreads();
    sh[tid] = x;
    __syncthreads();
  }
  if (tid < nb) bsum[tid] = sh[tid] - v;    // exclusive
}

// NOTE: deg_in and deg_inv alias (int buffer reinterpreted as float) —
// read-before-write in the same thread; no __restrict__ on these two.
__global__ __launch_bounds__(256) void scan_finish(const int* deg_in,
                                                   int* __restrict__ rowptr,
                                                   int* __restrict__ cursor,
                                                   float* deg_inv,
                                                   const int* __restrict__ bsum,
                                                   int N, int E) {
  int i = blockIdx.x * 256 + threadIdx.x;
  if (i >= N) return;
  int d = deg_in[i];
  int v = rowptr[i] + bsum[i >> 8];
  rowptr[i] = v;
  cursor[i] = v;
  deg_inv[i] = 1.0f / (float)(d > 1 ? d : 1);
  if (i == 0) rowptr[N] = E;
}

__global__ __launch_bounds__(256) void fill_csr(const int* __restrict__ src,
                                                const int* __restrict__ dst,
                                                int* __restrict__ cursor,
                                                int* __restrict__ colidx, int E) {
  int e = blockIdx.x * 256 + threadIdx.x;
  if (e < E) {
    int d = dst[e];
    int pos = atomicAdd(&cursor[d], 1);
    colidx[pos] = src[e];
  }
}

// ---------------- fused dual GEMM: t = h@Wl ; r = h@Wr + b ----------------
// K = 64 fixed. Block: 64-row tile, thread tile 4 rows x 8 cols.
// h tile in LDS stride 68 (2-way bank alias = free); Wl|Wr packed per-k row.
// h and r_out may alias in-place (same rows; loads complete before the
// __syncthreads that precedes all stores) — no __restrict__ on those two.

template <int DOUT>
__global__ __launch_bounds__(256) void gemm_dual(const float* h,
                                                 const float* __restrict__ Wl,
                                                 const float* __restrict__ Wr,
                                                 const float* __restrict__ bias,
                                                 float* __restrict__ t_out,
                                                 float* r_out, int N) {
  constexpr int TC = 2 * DOUT;        // 128 or 64 total output cols
  constexpr int NC = TC / 8;          // col-threads (8 cols each): 16 or 8
  constexpr int NT = 16 * NC;         // 256 or 128 threads
  __shared__ float hs[64 * 68];
  __shared__ float wsh[64 * TC];

  const int tid = threadIdx.x;
  const int row0 = blockIdx.x * 64;

  // stage h tile (64 x 64), clamped rows for the tail block
  for (int idx = tid; idx < 64 * 16; idx += NT) {
    int r = idx >> 4, c4 = (idx & 15) << 2;
    int gr = row0 + r;
    if (gr > N - 1) gr = N - 1;
    float4 v = *(const float4*)&h[(size_t)gr * 64 + c4];
    *(float4*)&hs[r * 68 + c4] = v;
  }
  // stage weights: wsh[k*TC + c] = Wl[k][c], wsh[k*TC + DOUT + c] = Wr[k][c]
  for (int idx = tid; idx < 16 * DOUT; idx += NT) {
    int f = idx << 2;
    int k = f / DOUT, c = f % DOUT;
    *(float4*)&wsh[k * TC + c] = *(const float4*)&Wl[f];
    *(float4*)&wsh[k * TC + DOUT + c] = *(const float4*)&Wr[f];
  }
  __syncthreads();

  const int cid = tid % NC;
  const int rid = tid / NC;
  float acc[4][8];
#pragma unroll
  for (int i = 0; i < 4; ++i)
#pragma unroll
    for (int m = 0; m < 8; ++m) acc[i][m] = 0.f;

#pragma unroll 8
  for (int k = 0; k < 64; ++k) {
    float4 w0 = *(const float4*)&wsh[k * TC + 4 * cid];
    float4 w1 = *(const float4*)&wsh[k * TC + DOUT + 4 * cid];
#pragma unroll
    for (int i = 0; i < 4; ++i) {
      float hv = hs[(4 * rid + i) * 68 + k];
      acc[i][0] += hv * w0.x; acc[i][1] += hv * w0.y;
      acc[i][2] += hv * w0.z; acc[i][3] += hv * w0.w;
      acc[i][4] += hv * w1.x; acc[i][5] += hv * w1.y;
      acc[i][6] += hv * w1.z; acc[i][7] += hv * w1.w;
    }
  }

  float4 bv = *(const float4*)&bias[4 * cid];
#pragma unroll
  for (int i = 0; i < 4; ++i) {
    int gr = row0 + 4 * rid + i;
    if (gr < N) {
      *(float4*)&t_out[(size_t)gr * DOUT + 4 * cid] =
          make_float4(acc[i][0], acc[i][1], acc[i][2], acc[i][3]);
      *(float4*)&r_out[(size_t)gr * DOUT + 4 * cid] =
          make_float4(acc[i][4] + bv.x, acc[i][5] + bv.y,
                      acc[i][6] + bv.z, acc[i][7] + bv.w);
    }
  }
}

// ---------------- gather: out = elu?(deg_inv * sum_{src in N(dst)} t[src] + r[dst]) --
// One DOUT-lane subgroup per node, lane = feature. r and out alias in place
// (same address, read feeds the store => dependence-ordered); no restrict there.

template <int DOUT, bool DO_ELU>
__global__ __launch_bounds__(256) void gather_mean(const float* __restrict__ t,
                                                   const float* r,
                                                   const float* __restrict__ deg_inv,
                                                   const int* __restrict__ rowptr,
                                                   const int* __restrict__ colidx,
                                                   float* out, int N) {
  int node = blockIdx.x * (256 / DOUT) + threadIdx.x / DOUT;
  int lane = threadIdx.x & (DOUT - 1);
  if (node >= N) return;
  int b = rowptr[node];
  int e = rowptr[node + 1];
  float a0 = 0.f, a1 = 0.f;
  int i = b;
  for (; i + 2 <= e; i += 2) {
    int s0 = colidx[i];
    int s1 = colidx[i + 1];
    a0 += t[(size_t)s0 * DOUT + lane];
    a1 += t[(size_t)s1 * DOUT + lane];
  }
  if (i < e) a0 += t[(size_t)colidx[i] * DOUT + lane];
  float acc = (a0 + a1) * deg_inv[node] + r[(size_t)node * DOUT + lane];
  if (DO_ELU) acc = acc > 0.f ? acc : (expf(acc) - 1.f);
  out[(size_t)node * DOUT + lane] = acc;
}

// ---------------- launch ----------------

extern "C" void kernel_launch(void* const* d_in, const int* in_sizes, int n_in,
                              void* d_out, int out_size, void* d_ws, size_t ws_size,
                              hipStream_t stream) {
  const float* x   = (const float*)d_in[0];
  const int*   ei  = (const int*)d_in[1];
  const float* Wl0 = (const float*)d_in[2];
  const float* Wr0 = (const float*)d_in[3];
  const float* b0  = (const float*)d_in[4];
  const float* Wl1 = (const float*)d_in[5];
  const float* Wr1 = (const float*)d_in[6];
  const float* b1  = (const float*)d_in[7];
  const float* Wl2 = (const float*)d_in[8];
  const float* Wr2 = (const float*)d_in[9];
  const float* b2  = (const float*)d_in[10];
  float* out = (float*)d_out;

  const int N = in_sizes[0] / 64;   // 100000
  const int E = in_sizes[1] / 2;    // 1600000
  const int* srcv = ei;
  const int* dstv = ei + E;

  auto al = [](size_t v) { return (v + 255) & ~(size_t)255; };
  char* w = (char*)d_ws;
  size_t oDeg = 0;
  size_t oRow = oDeg + al(4 * (size_t)(N + 1));
  size_t oCur = oRow + al(4 * (size_t)(N + 1));
  size_t oBs  = oCur + al(4 * (size_t)N);
  size_t oCol = oBs + al(4 * 512);
  size_t oP   = oCol + al(4 * (size_t)E);
  size_t oQ   = oP + al(4 * (size_t)N * 64);
  // total = oQ + 4*N*64  (~56 MiB)

  int*   deg     = (int*)(w + oDeg);
  float* deg_inv = (float*)(w + oDeg);   // aliases deg after scan_finish
  int*   rowptr  = (int*)(w + oRow);
  int*   cursor  = (int*)(w + oCur);
  int*   bsum    = (int*)(w + oBs);
  int*   colidx  = (int*)(w + oCol);
  float* P       = (float*)(w + oP);     // t buffer [N][<=64]
  float* Q       = (float*)(w + oQ);     // h / r buffer [N][64]

  hipMemsetAsync(deg, 0, (size_t)N * 4, stream);

  int ebl = (E + 255) / 256;
  int nb  = (N + 255) / 256;
  count_deg<<<ebl, 256, 0, stream>>>(dstv, deg, E);
  scan_blocks<<<nb, 256, 0, stream>>>(deg, rowptr, bsum, N);
  scan_tops<<<1, 512, 0, stream>>>(bsum, nb);
  scan_finish<<<nb, 256, 0, stream>>>(deg, rowptr, cursor, deg_inv, bsum, N, E);
  fill_csr<<<ebl, 256, 0, stream>>>(srcv, dstv, cursor, colidx, E);

  int gb = (N + 63) / 64;
  // layer 0: x -> t=P, r=Q ; gather -> h1 in Q (in-place over r)
  gemm_dual<64><<<gb, 256, 0, stream>>>(x, Wl0, Wr0, b0, P, Q, N);
  gather_mean<64, true><<<(N + 3) / 4, 256, 0, stream>>>(P, Q, deg_inv, rowptr, colidx, Q, N);
  // layer 1: Q -> t=P, r=Q (in-place) ; gather -> h2 in Q
  gemm_dual<64><<<gb, 256, 0, stream>>>(Q, Wl1, Wr1, b1, P, Q, N);
  gather_mean<64, true><<<(N + 3) / 4, 256, 0, stream>>>(P, Q, deg_inv, rowptr, colidx, Q, N);
  // layer 2: Q -> t=P (N x 32), r -> d_out ; gather -> d_out (no ELU)
  gemm_dual<32><<<gb, 128, 0, stream>>>(Q, Wl2, Wr2, b2, P, out, N);
  gather_mean<32, false><<<(N + 7) / 8, 256, 0, stream>>>(P, out, deg_inv, rowptr, colidx, out, N);
}

// Round 2
// 466.983 us; speedup vs baseline: 1.2845x; 1.2845x over previous
//
#include <hip/hip_runtime.h>
#include <cstdint>
#include <cstddef>

// GraphSAGE 3-layer, N=100000 nodes, E=1600000 edges, dims 64->64->64->32.
// Transform-then-aggregate; CSR built once per launch via bucketed counting
// sort (write-local, LDS-histogram based), reused for all 3 layers.

constexpr int BW = 128;      // nodes per bucket (power of 2)
constexpr int LOGBW = 7;
// NB = ceil(N/BW) = 782 for N=100000; LDS hist arrays sized 1024 (N<=131072).

// ---------------- CSR build: bucketed counting sort ----------------

// Pass 1: per-block LDS histogram over buckets, flush with global atomics.
__global__ __launch_bounds__(256) void bucket_count(const int* __restrict__ dst,
                                                    int* __restrict__ bcnt,
                                                    int NB, int E) {
  __shared__ int h[1024];
  for (int i = threadIdx.x; i < NB; i += 256) h[i] = 0;
  __syncthreads();
  int e0 = blockIdx.x * 4096;
  int e1 = min(E, e0 + 4096);
  for (int e = e0 + (int)threadIdx.x; e < e1; e += 256)
    atomicAdd(&h[dst[e] >> LOGBW], 1);
  __syncthreads();
  for (int i = threadIdx.x; i < NB; i += 256) {
    int c = h[i];
    if (c) atomicAdd(&bcnt[i], c);
  }
}

// Pass 2: single-block exclusive scan of bucket counts (NB <= 1024).
__global__ __launch_bounds__(1024) void bucket_scan(const int* __restrict__ bcnt,
                                                    int* __restrict__ boff,
                                                    int* __restrict__ bcur,
                                                    int* __restrict__ rowptr,
                                                    int NB, int N, int E) {
  __shared__ int sh[1024];
  int tid = threadIdx.x;
  int v = (tid < NB) ? bcnt[tid] : 0;
  sh[tid] = v;
  __syncthreads();
  for (int off = 1; off < 1024; off <<= 1) {
    int x = sh[tid];
    if (tid >= off) x += sh[tid - off];
    __syncthreads();
    sh[tid] = x;
    __syncthreads();
  }
  if (tid < NB) {
    int ex = sh[tid] - v;
    boff[tid] = ex;
    bcur[tid] = ex;
  }
  if (tid == 0) {
    boff[NB] = E;
    rowptr[N] = E;
  }
}

// Pass 3: bin edges by bucket. Each block counts its 4096-edge chunk in LDS,
// reserves a range per touched bucket (1 global atomic each), then scatters
// packed words (src | dstlocal<<17) into bucket-contiguous regions.
__global__ __launch_bounds__(256) void bucket_bin(const int* __restrict__ src,
                                                  const int* __restrict__ dst,
                                                  int* __restrict__ bcur,
                                                  unsigned int* __restrict__ binned,
                                                  int NB, int E) {
  __shared__ int h[1024];
  for (int i = threadIdx.x; i < NB; i += 256) h[i] = 0;
  __syncthreads();
  int e0 = blockIdx.x * 4096;
  int e1 = min(E, e0 + 4096);
  for (int e = e0 + (int)threadIdx.x; e < e1; e += 256)
    atomicAdd(&h[dst[e] >> LOGBW], 1);
  __syncthreads();
  for (int i = threadIdx.x; i < NB; i += 256) {
    int c = h[i];
    h[i] = c ? atomicAdd(&bcur[i], c) : 0;   // hist slot becomes write cursor
  }
  __syncthreads();
  for (int e = e0 + (int)threadIdx.x; e < e1; e += 256) {
    int d = dst[e];
    int b = d >> LOGBW;
    int pos = atomicAdd(&h[b], 1);
    binned[pos] = (unsigned)src[e] | ((unsigned)(d & (BW - 1)) << 17);
  }
}

// Pass 4: one block per bucket -> rowptr, deg_inv, colidx (all writes local
// to the bucket's contiguous colidx span).
__global__ __launch_bounds__(256) void bucket_csr(const unsigned int* __restrict__ binned,
                                                  const int* __restrict__ boff,
                                                  int* __restrict__ rowptr,
                                                  float* __restrict__ deg_inv,
                                                  int* __restrict__ colidx,
                                                  int N) {
  __shared__ int cnt[BW];
  __shared__ int sc[BW];
  __shared__ int cur[BW];
  int b = blockIdx.x;
  int tid = threadIdx.x;
  if (tid < BW) cnt[tid] = 0;
  __syncthreads();
  int e0 = boff[b], e1 = boff[b + 1];
  for (int e = e0 + tid; e < e1; e += 256)
    atomicAdd(&cnt[binned[e] >> 17], 1);
  __syncthreads();
  int v = (tid < BW) ? cnt[tid] : 0;
  if (tid < BW) sc[tid] = v;
  __syncthreads();
  for (int off = 1; off < BW; off <<= 1) {
    int y = 0;
    if (tid < BW) {
      y = sc[tid];
      if (tid >= off) y += sc[tid - off];
    }
    __syncthreads();
    if (tid < BW) sc[tid] = y;
    __syncthreads();
  }
  if (tid < BW) {
    int ex = sc[tid] - v;                     // exclusive prefix
    cur[tid] = ex;
    int gn = b * BW + tid;
    if (gn < N) {
      rowptr[gn] = e0 + ex;
      deg_inv[gn] = 1.0f / (float)(v > 1 ? v : 1);
    }
  }
  __syncthreads();
  for (int e = e0 + tid; e < e1; e += 256) {
    unsigned p = binned[e];
    int dl = (int)(p >> 17);
    int s = (int)(p & 0x1FFFFu);
    int l = atomicAdd(&cur[dl], 1);
    colidx[e0 + l] = s;
  }
}

// ---------------- fused dual GEMM: t = h@Wl ; r = h@Wr + b ----------------
// K = 64 fixed. Block: 64-row tile, thread tile 4 rows x 8 cols.
// h and r_out may alias in-place (loads complete before stores via the
// barrier) — no __restrict__ on those two.

template <int DOUT>
__global__ __launch_bounds__(256) void gemm_dual(const float* h,
                                                 const float* __restrict__ Wl,
                                                 const float* __restrict__ Wr,
                                                 const float* __restrict__ bias,
                                                 float* __restrict__ t_out,
                                                 float* r_out, int N) {
  constexpr int TC = 2 * DOUT;
  constexpr int NC = TC / 8;
  constexpr int NT = 16 * NC;
  __shared__ float hs[64 * 68];
  __shared__ float wsh[64 * TC];

  const int tid = threadIdx.x;
  const int row0 = blockIdx.x * 64;

  for (int idx = tid; idx < 64 * 16; idx += NT) {
    int r = idx >> 4, c4 = (idx & 15) << 2;
    int gr = row0 + r;
    if (gr > N - 1) gr = N - 1;
    float4 v = *(const float4*)&h[(size_t)gr * 64 + c4];
    *(float4*)&hs[r * 68 + c4] = v;
  }
  for (int idx = tid; idx < 16 * DOUT; idx += NT) {
    int f = idx << 2;
    int k = f / DOUT, c = f % DOUT;
    *(float4*)&wsh[k * TC + c] = *(const float4*)&Wl[f];
    *(float4*)&wsh[k * TC + DOUT + c] = *(const float4*)&Wr[f];
  }
  __syncthreads();

  const int cid = tid % NC;
  const int rid = tid / NC;
  float acc[4][8];
#pragma unroll
  for (int i = 0; i < 4; ++i)
#pragma unroll
    for (int m = 0; m < 8; ++m) acc[i][m] = 0.f;

#pragma unroll 8
  for (int k = 0; k < 64; ++k) {
    float4 w0 = *(const float4*)&wsh[k * TC + 4 * cid];
    float4 w1 = *(const float4*)&wsh[k * TC + DOUT + 4 * cid];
#pragma unroll
    for (int i = 0; i < 4; ++i) {
      float hv = hs[(4 * rid + i) * 68 + k];
      acc[i][0] += hv * w0.x; acc[i][1] += hv * w0.y;
      acc[i][2] += hv * w0.z; acc[i][3] += hv * w0.w;
      acc[i][4] += hv * w1.x; acc[i][5] += hv * w1.y;
      acc[i][6] += hv * w1.z; acc[i][7] += hv * w1.w;
    }
  }

  float4 bv = *(const float4*)&bias[4 * cid];
#pragma unroll
  for (int i = 0; i < 4; ++i) {
    int gr = row0 + 4 * rid + i;
    if (gr < N) {
      *(float4*)&t_out[(size_t)gr * DOUT + 4 * cid] =
          make_float4(acc[i][0], acc[i][1], acc[i][2], acc[i][3]);
      *(float4*)&r_out[(size_t)gr * DOUT + 4 * cid] =
          make_float4(acc[i][4] + bv.x, acc[i][5] + bv.y,
                      acc[i][6] + bv.z, acc[i][7] + bv.w);
    }
  }
}

// ---------------- gather: out = elu?(deg_inv * sum t[src] + r[dst]) -------

template <int DOUT, bool DO_ELU>
__global__ __launch_bounds__(256) void gather_mean(const float* __restrict__ t,
                                                   const float* r,
                                                   const float* __restrict__ deg_inv,
                                                   const int* __restrict__ rowptr,
                                                   const int* __restrict__ colidx,
                                                   float* out, int N) {
  int node = blockIdx.x * (256 / DOUT) + threadIdx.x / DOUT;
  int lane = threadIdx.x & (DOUT - 1);
  if (node >= N) return;
  int b = rowptr[node];
  int e = rowptr[node + 1];
  float a0 = 0.f, a1 = 0.f;
  int i = b;
  for (; i + 2 <= e; i += 2) {
    int s0 = colidx[i];
    int s1 = colidx[i + 1];
    a0 += t[(size_t)s0 * DOUT + lane];
    a1 += t[(size_t)s1 * DOUT + lane];
  }
  if (i < e) a0 += t[(size_t)colidx[i] * DOUT + lane];
  float acc = (a0 + a1) * deg_inv[node] + r[(size_t)node * DOUT + lane];
  if (DO_ELU) acc = acc > 0.f ? acc : (expf(acc) - 1.f);
  out[(size_t)node * DOUT + lane] = acc;
}

// ---------------- launch ----------------

extern "C" void kernel_launch(void* const* d_in, const int* in_sizes, int n_in,
                              void* d_out, int out_size, void* d_ws, size_t ws_size,
                              hipStream_t stream) {
  const float* x   = (const float*)d_in[0];
  const int*   ei  = (const int*)d_in[1];
  const float* Wl0 = (const float*)d_in[2];
  const float* Wr0 = (const float*)d_in[3];
  const float* b0  = (const float*)d_in[4];
  const float* Wl1 = (const float*)d_in[5];
  const float* Wr1 = (const float*)d_in[6];
  const float* b1  = (const float*)d_in[7];
  const float* Wl2 = (const float*)d_in[8];
  const float* Wr2 = (const float*)d_in[9];
  const float* b2  = (const float*)d_in[10];
  float* out = (float*)d_out;

  const int N = in_sizes[0] / 64;   // 100000
  const int E = in_sizes[1] / 2;    // 1600000
  const int* srcv = ei;
  const int* dstv = ei + E;
  const int NB = (N + BW - 1) >> LOGBW;   // 782

  auto al = [](size_t v) { return (v + 255) & ~(size_t)255; };
  char* w = (char*)d_ws;
  size_t oBcnt = 0;
  size_t oBoff = oBcnt + al(4 * (size_t)NB);
  size_t oBcur = oBoff + al(4 * (size_t)(NB + 1));
  size_t oRow  = oBcur + al(4 * (size_t)NB);
  size_t oDinv = oRow + al(4 * (size_t)(N + 1));
  size_t oBin  = oDinv + al(4 * (size_t)N);
  size_t oCol  = oBin + al(4 * (size_t)E);
  size_t oP    = oCol + al(4 * (size_t)E);
  size_t oQ    = oP + al(4 * (size_t)N * 64);
  // total = oQ + 4*N*64  (~65 MiB)

  int*      bcnt    = (int*)(w + oBcnt);
  int*      boff    = (int*)(w + oBoff);
  int*      bcur    = (int*)(w + oBcur);
  int*      rowptr  = (int*)(w + oRow);
  float*    deg_inv = (float*)(w + oDinv);
  unsigned* binned  = (unsigned*)(w + oBin);
  int*      colidx  = (int*)(w + oCol);
  float*    P       = (float*)(w + oP);
  float*    Q       = (float*)(w + oQ);

  hipMemsetAsync(bcnt, 0, (size_t)NB * 4, stream);

  int cbl = (E + 4095) / 4096;
  bucket_count<<<cbl, 256, 0, stream>>>(dstv, bcnt, NB, E);
  bucket_scan<<<1, 1024, 0, stream>>>(bcnt, boff, bcur, rowptr, NB, N, E);
  bucket_bin<<<cbl, 256, 0, stream>>>(srcv, dstv, bcur, binned, NB, E);
  bucket_csr<<<NB, 256, 0, stream>>>(binned, boff, rowptr, deg_inv, colidx, N);

  int gb = (N + 63) / 64;
  gemm_dual<64><<<gb, 256, 0, stream>>>(x, Wl0, Wr0, b0, P, Q, N);
  gather_mean<64, true><<<(N + 3) / 4, 256, 0, stream>>>(P, Q, deg_inv, rowptr, colidx, Q, N);
  gemm_dual<64><<<gb, 256, 0, stream>>>(Q, Wl1, Wr1, b1, P, Q, N);
  gather_mean<64, true><<<(N + 3) / 4, 256, 0, stream>>>(P, Q, deg_inv, rowptr, colidx, Q, N);
  gemm_dual<32><<<gb, 128, 0, stream>>>(Q, Wl2, Wr2, b2, P, out, N);
  gather_mean<32, false><<<(N + 7) / 8, 256, 0, stream>>>(P, out, deg_inv, rowptr, colidx, out, N);
}

// Round 3
// 344.423 us; speedup vs baseline: 1.7416x; 1.3558x over previous
//
#include <hip/hip_runtime.h>
#include <cstdint>
#include <cstddef>

// GraphSAGE 3-layer, N=100000 nodes, E=1600000 edges, dims 64->64->64->32.
// Transform-then-aggregate; CSR built once per launch via bucketed counting
// sort; gather reads bf16-packed transformed features (halves the random-read
// footprint, which is the measured bottleneck), accumulates fp32.

constexpr int BW = 128;      // nodes per bucket (power of 2)
constexpr int LOGBW = 7;
// NB = ceil(N/BW) = 782 for N=100000; LDS hist arrays sized 1024 (N<=131072).

__device__ inline unsigned short f2bf(float f) {
  unsigned u = __builtin_bit_cast(unsigned, f);
  u += 0x7FFFu + ((u >> 16) & 1u);          // round-to-nearest-even
  return (unsigned short)(u >> 16);
}
__device__ inline float bf2f(unsigned short b) {
  unsigned u = ((unsigned)b) << 16;
  return __builtin_bit_cast(float, u);
}

// ---------------- CSR build: bucketed counting sort ----------------

__global__ __launch_bounds__(256) void bucket_count(const int* __restrict__ dst,
                                                    int* __restrict__ bcnt,
                                                    int NB, int E) {
  __shared__ int h[1024];
  for (int i = threadIdx.x; i < NB; i += 256) h[i] = 0;
  __syncthreads();
  int e0 = blockIdx.x * 4096;
  int e1 = min(E, e0 + 4096);
  for (int e = e0 + (int)threadIdx.x; e < e1; e += 256)
    atomicAdd(&h[dst[e] >> LOGBW], 1);
  __syncthreads();
  for (int i = threadIdx.x; i < NB; i += 256) {
    int c = h[i];
    if (c) atomicAdd(&bcnt[i], c);
  }
}

__global__ __launch_bounds__(1024) void bucket_scan(const int* __restrict__ bcnt,
                                                    int* __restrict__ boff,
                                                    int* __restrict__ bcur,
                                                    int* __restrict__ rowptr,
                                                    int NB, int N, int E) {
  __shared__ int sh[1024];
  int tid = threadIdx.x;
  int v = (tid < NB) ? bcnt[tid] : 0;
  sh[tid] = v;
  __syncthreads();
  for (int off = 1; off < 1024; off <<= 1) {
    int x = sh[tid];
    if (tid >= off) x += sh[tid - off];
    __syncthreads();
    sh[tid] = x;
    __syncthreads();
  }
  if (tid < NB) {
    int ex = sh[tid] - v;
    boff[tid] = ex;
    bcur[tid] = ex;
  }
  if (tid == 0) {
    boff[NB] = E;
    rowptr[N] = E;
  }
}

__global__ __launch_bounds__(256) void bucket_bin(const int* __restrict__ src,
                                                  const int* __restrict__ dst,
                                                  int* __restrict__ bcur,
                                                  unsigned int* __restrict__ binned,
                                                  int NB, int E) {
  __shared__ int h[1024];
  for (int i = threadIdx.x; i < NB; i += 256) h[i] = 0;
  __syncthreads();
  int e0 = blockIdx.x * 4096;
  int e1 = min(E, e0 + 4096);
  for (int e = e0 + (int)threadIdx.x; e < e1; e += 256)
    atomicAdd(&h[dst[e] >> LOGBW], 1);
  __syncthreads();
  for (int i = threadIdx.x; i < NB; i += 256) {
    int c = h[i];
    h[i] = c ? atomicAdd(&bcur[i], c) : 0;   // hist slot becomes write cursor
  }
  __syncthreads();
  for (int e = e0 + (int)threadIdx.x; e < e1; e += 256) {
    int d = dst[e];
    int b = d >> LOGBW;
    int pos = atomicAdd(&h[b], 1);
    binned[pos] = (unsigned)src[e] | ((unsigned)(d & (BW - 1)) << 17);
  }
}

__global__ __launch_bounds__(256) void bucket_csr(const unsigned int* __restrict__ binned,
                                                  const int* __restrict__ boff,
                                                  int* __restrict__ rowptr,
                                                  float* __restrict__ deg_inv,
                                                  int* __restrict__ colidx,
                                                  int N) {
  __shared__ int cnt[BW];
  __shared__ int sc[BW];
  __shared__ int cur[BW];
  int b = blockIdx.x;
  int tid = threadIdx.x;
  if (tid < BW) cnt[tid] = 0;
  __syncthreads();
  int e0 = boff[b], e1 = boff[b + 1];
  for (int e = e0 + tid; e < e1; e += 256)
    atomicAdd(&cnt[binned[e] >> 17], 1);
  __syncthreads();
  int v = (tid < BW) ? cnt[tid] : 0;
  if (tid < BW) sc[tid] = v;
  __syncthreads();
  for (int off = 1; off < BW; off <<= 1) {
    int y = 0;
    if (tid < BW) {
      y = sc[tid];
      if (tid >= off) y += sc[tid - off];
    }
    __syncthreads();
    if (tid < BW) sc[tid] = y;
    __syncthreads();
  }
  if (tid < BW) {
    int ex = sc[tid] - v;
    cur[tid] = ex;
    int gn = b * BW + tid;
    if (gn < N) {
      rowptr[gn] = e0 + ex;
      deg_inv[gn] = 1.0f / (float)(v > 1 ? v : 1);
    }
  }
  __syncthreads();
  for (int e = e0 + tid; e < e1; e += 256) {
    unsigned p = binned[e];
    int dl = (int)(p >> 17);
    int s = (int)(p & 0x1FFFFu);
    int l = atomicAdd(&cur[dl], 1);
    colidx[e0 + l] = s;
  }
}

// ---------------- fused dual GEMM: t = bf16(h@Wl) ; r = h@Wr + b ----------
// K = 64 fixed. Block: 64-row tile, thread tile 4 rows x 8 cols (4 t + 4 r).
// h and r_out may alias in-place — no __restrict__ on those two.

template <int DOUT>
__global__ __launch_bounds__(256) void gemm_dual(const float* h,
                                                 const float* __restrict__ Wl,
                                                 const float* __restrict__ Wr,
                                                 const float* __restrict__ bias,
                                                 unsigned short* __restrict__ t_out,
                                                 float* r_out, int N) {
  constexpr int TC = 2 * DOUT;
  constexpr int NC = TC / 8;
  constexpr int NT = 16 * NC;
  __shared__ float hs[64 * 68];
  __shared__ float wsh[64 * TC];

  const int tid = threadIdx.x;
  const int row0 = blockIdx.x * 64;

  for (int idx = tid; idx < 64 * 16; idx += NT) {
    int r = idx >> 4, c4 = (idx & 15) << 2;
    int gr = row0 + r;
    if (gr > N - 1) gr = N - 1;
    float4 v = *(const float4*)&h[(size_t)gr * 64 + c4];
    *(float4*)&hs[r * 68 + c4] = v;
  }
  for (int idx = tid; idx < 16 * DOUT; idx += NT) {
    int f = idx << 2;
    int k = f / DOUT, c = f % DOUT;
    *(float4*)&wsh[k * TC + c] = *(const float4*)&Wl[f];
    *(float4*)&wsh[k * TC + DOUT + c] = *(const float4*)&Wr[f];
  }
  __syncthreads();

  const int cid = tid % NC;
  const int rid = tid / NC;
  float acc[4][8];
#pragma unroll
  for (int i = 0; i < 4; ++i)
#pragma unroll
    for (int m = 0; m < 8; ++m) acc[i][m] = 0.f;

#pragma unroll 8
  for (int k = 0; k < 64; ++k) {
    float4 w0 = *(const float4*)&wsh[k * TC + 4 * cid];
    float4 w1 = *(const float4*)&wsh[k * TC + DOUT + 4 * cid];
#pragma unroll
    for (int i = 0; i < 4; ++i) {
      float hv = hs[(4 * rid + i) * 68 + k];
      acc[i][0] += hv * w0.x; acc[i][1] += hv * w0.y;
      acc[i][2] += hv * w0.z; acc[i][3] += hv * w0.w;
      acc[i][4] += hv * w1.x; acc[i][5] += hv * w1.y;
      acc[i][6] += hv * w1.z; acc[i][7] += hv * w1.w;
    }
  }

  float4 bv = *(const float4*)&bias[4 * cid];
#pragma unroll
  for (int i = 0; i < 4; ++i) {
    int gr = row0 + 4 * rid + i;
    if (gr < N) {
      ushort4 tv;
      tv.x = f2bf(acc[i][0]); tv.y = f2bf(acc[i][1]);
      tv.z = f2bf(acc[i][2]); tv.w = f2bf(acc[i][3]);
      *(ushort4*)&t_out[(size_t)gr * DOUT + 4 * cid] = tv;
      *(float4*)&r_out[(size_t)gr * DOUT + 4 * cid] =
          make_float4(acc[i][4] + bv.x, acc[i][5] + bv.y,
                      acc[i][6] + bv.z, acc[i][7] + bv.w);
    }
  }
}

// ------ gather: out = elu?(deg_inv * sum t[src] + r[dst]), t is bf16 ------
// DOUT/2 lanes per node; each lane owns a packed pair of features (one uint
// load per edge). r and out alias in place; no restrict on those two.

template <int DOUT, bool DO_ELU>
__global__ __launch_bounds__(256) void gather_mean(const unsigned int* __restrict__ t,
                                                   const float* r,
                                                   const float* __restrict__ deg_inv,
                                                   const int* __restrict__ rowptr,
                                                   const int* __restrict__ colidx,
                                                   float* out, int N) {
  constexpr int L = DOUT / 2;                 // lanes per node: 32 or 16
  int node = blockIdx.x * (256 / L) + threadIdx.x / L;
  int lane = threadIdx.x & (L - 1);
  if (node >= N) return;
  int b = rowptr[node];
  int e = rowptr[node + 1];
  float s0 = 0.f, s1 = 0.f;
  int i = b;
  for (; i + 4 <= e; i += 4) {
    int c0 = colidx[i], c1 = colidx[i + 1], c2 = colidx[i + 2], c3 = colidx[i + 3];
    unsigned v0 = t[(size_t)c0 * L + lane];
    unsigned v1 = t[(size_t)c1 * L + lane];
    unsigned v2 = t[(size_t)c2 * L + lane];
    unsigned v3 = t[(size_t)c3 * L + lane];
    s0 += bf2f((unsigned short)(v0 & 0xFFFFu)) + bf2f((unsigned short)(v1 & 0xFFFFu))
        + bf2f((unsigned short)(v2 & 0xFFFFu)) + bf2f((unsigned short)(v3 & 0xFFFFu));
    s1 += bf2f((unsigned short)(v0 >> 16)) + bf2f((unsigned short)(v1 >> 16))
        + bf2f((unsigned short)(v2 >> 16)) + bf2f((unsigned short)(v3 >> 16));
  }
  for (; i < e; ++i) {
    unsigned v = t[(size_t)colidx[i] * L + lane];
    s0 += bf2f((unsigned short)(v & 0xFFFFu));
    s1 += bf2f((unsigned short)(v >> 16));
  }
  float dv = deg_inv[node];
  float2 rv = *(const float2*)&r[(size_t)node * DOUT + 2 * lane];
  float a0 = s0 * dv + rv.x;
  float a1 = s1 * dv + rv.y;
  if (DO_ELU) {
    a0 = a0 > 0.f ? a0 : (expf(a0) - 1.f);
    a1 = a1 > 0.f ? a1 : (expf(a1) - 1.f);
  }
  *(float2*)&out[(size_t)node * DOUT + 2 * lane] = make_float2(a0, a1);
}

// ---------------- launch ----------------

extern "C" void kernel_launch(void* const* d_in, const int* in_sizes, int n_in,
                              void* d_out, int out_size, void* d_ws, size_t ws_size,
                              hipStream_t stream) {
  const float* x   = (const float*)d_in[0];
  const int*   ei  = (const int*)d_in[1];
  const float* Wl0 = (const float*)d_in[2];
  const float* Wr0 = (const float*)d_in[3];
  const float* b0  = (const float*)d_in[4];
  const float* Wl1 = (const float*)d_in[5];
  const float* Wr1 = (const float*)d_in[6];
  const float* b1  = (const float*)d_in[7];
  const float* Wl2 = (const float*)d_in[8];
  const float* Wr2 = (const float*)d_in[9];
  const float* b2  = (const float*)d_in[10];
  float* out = (float*)d_out;

  const int N = in_sizes[0] / 64;   // 100000
  const int E = in_sizes[1] / 2;    // 1600000
  const int* srcv = ei;
  const int* dstv = ei + E;
  const int NB = (N + BW - 1) >> LOGBW;   // 782

  auto al = [](size_t v) { return (v + 255) & ~(size_t)255; };
  char* w = (char*)d_ws;
  size_t oBcnt = 0;
  size_t oBoff = oBcnt + al(4 * (size_t)NB);
  size_t oBcur = oBoff + al(4 * (size_t)(NB + 1));
  size_t oRow  = oBcur + al(4 * (size_t)NB);
  size_t oDinv = oRow + al(4 * (size_t)(N + 1));
  size_t oBin  = oDinv + al(4 * (size_t)N);
  size_t oCol  = oBin + al(4 * (size_t)E);
  size_t oP    = oCol + al(4 * (size_t)E);
  size_t oQ    = oP + al(2 * (size_t)N * 64);   // P is bf16 now
  // total = oQ + 4*N*64  (~52 MiB)

  int*            bcnt    = (int*)(w + oBcnt);
  int*            boff    = (int*)(w + oBoff);
  int*            bcur    = (int*)(w + oBcur);
  int*            rowptr  = (int*)(w + oRow);
  float*          deg_inv = (float*)(w + oDinv);
  unsigned*       binned  = (unsigned*)(w + oBin);
  int*            colidx  = (int*)(w + oCol);
  unsigned short* P       = (unsigned short*)(w + oP);   // bf16 t buffer
  float*          Q       = (float*)(w + oQ);

  hipMemsetAsync(bcnt, 0, (size_t)NB * 4, stream);

  int cbl = (E + 4095) / 4096;
  bucket_count<<<cbl, 256, 0, stream>>>(dstv, bcnt, NB, E);
  bucket_scan<<<1, 1024, 0, stream>>>(bcnt, boff, bcur, rowptr, NB, N, E);
  bucket_bin<<<cbl, 256, 0, stream>>>(srcv, dstv, bcur, binned, NB, E);
  bucket_csr<<<NB, 256, 0, stream>>>(binned, boff, rowptr, deg_inv, colidx, N);

  int gb = (N + 63) / 64;
  gemm_dual<64><<<gb, 256, 0, stream>>>(x, Wl0, Wr0, b0, P, Q, N);
  gather_mean<64, true><<<(N + 7) / 8, 256, 0, stream>>>((const unsigned*)P, Q, deg_inv, rowptr, colidx, Q, N);
  gemm_dual<64><<<gb, 256, 0, stream>>>(Q, Wl1, Wr1, b1, P, Q, N);
  gather_mean<64, true><<<(N + 7) / 8, 256, 0, stream>>>((const unsigned*)P, Q, deg_inv, rowptr, colidx, Q, N);
  gemm_dual<32><<<gb, 128, 0, stream>>>(Q, Wl2, Wr2, b2, P, out, N);
  gather_mean<32, false><<<(N + 15) / 16, 256, 0, stream>>>((const unsigned*)P, out, deg_inv, rowptr, colidx, out, N);
}